// Round 4
// baseline (474.761 us; speedup 1.0000x reference)
//
#include <hip/hip_runtime.h>

// VQBlock: x[16,64,64,256] fp32, dict[256,1024] fp32.
// out = concat(q_st flat [16777216], loss [1]) fp32.
//
// Round 4: f16 MFMA fast path, 32 rows/wave (2 row-tiles per B-frag read),
// XOR-swizzled bstage (2-way banks = free), 5-op/candidate top-2 scan
// (med3/min + SGPR index), software-pipelined staging, fused prep kernel.
// Proven np-faithful fp32 rescan for rows with fast top-2 gap < EPS_TIE.

#define NROWS   65536
#define DIM     256
#define NCODE   1024
#define RPB     64
#define EPS_TIE 4e-3f

typedef _Float16 half8 __attribute__((ext_vector_type(8)));
typedef float    f32x4 __attribute__((ext_vector_type(4)));

// ---------- fused prep kernel ----------
// blocks 0..255: transpose dict -> dictT[k][d]
// blocks 256..259: dictnorm[k] = sum_d dict[d][k]^2 (bit-identical to R3)
// blocks 260..291: pack dict -> f16 MFMA-B layout packB (bit-identical values)
__global__ __launch_bounds__(256) void k_prep(const float* __restrict__ dict,
                                              float* __restrict__ dictT,
                                              float* __restrict__ dictnorm,
                                              unsigned short* __restrict__ packB) {
    const int b = blockIdx.x, tid = threadIdx.x;
    if (b < 256) {
        int t = b * 256 + tid;
#pragma unroll
        for (int i = 0; i < 4; ++i) {
            int e = i * 65536 + t;                    // coalesced read
            int d = e >> 10, k = e & 1023;
            dictT[k * DIM + d] = dict[e];
        }
    } else if (b < 260) {
        int k = (b - 256) * 256 + tid;
        float s = 0.f;
#pragma unroll 8
        for (int d = 0; d < DIM; ++d) {
            float v = dict[d * NCODE + k];
            s = fmaf(v, v, s);
        }
        dictnorm[k] = s;
    } else {
        __shared__ float tile[32][257];
        const int pb = b - 260;                       // 0..31
        const int kk = pb >> 2, kg = pb & 3;
#pragma unroll
        for (int dl = 0; dl < 32; ++dl)
            tile[dl][tid] = dict[(kk * 32 + dl) * NCODE + kg * 256 + tid];  // coalesced
        __syncthreads();
        // code n = kg*256+tid: 32 dims as q-major/j-minor f16, contiguous 64B per code
        unsigned int* dst = (unsigned int*)(packB + (size_t)kk * 32768 + (size_t)(kg * 256 + tid) * 32);
#pragma unroll
        for (int q = 0; q < 4; ++q) {
            unsigned int w[4];
#pragma unroll
            for (int p = 0; p < 4; ++p) {
                _Float16 h0 = (_Float16)tile[q * 8 + p * 2 + 0][tid];
                _Float16 h1 = (_Float16)tile[q * 8 + p * 2 + 1][tid];
                unsigned short u0 = *(unsigned short*)&h0;
                unsigned short u1 = *(unsigned short*)&h1;
                w[p] = (unsigned int)u0 | ((unsigned int)u1 << 16);
            }
            *(uint4*)(dst + q * 4) = make_uint4(w[0], w[1], w[2], w[3]);
        }
    }
}

// np pairwise sum of squares of 128 contiguous elements
__device__ __forceinline__ float np_pairwise_sq_128(const float* a) {
    float r[8];
#pragma unroll
    for (int j = 0; j < 8; ++j) {
        float v = a[j];
        r[j] = __fmul_rn(v, v);
    }
    for (int i = 8; i < 128; i += 8) {
#pragma unroll
        for (int j = 0; j < 8; ++j) {
            float v = a[i + j];
            r[j] = __fadd_rn(r[j], __fmul_rn(v, v));
        }
    }
    return __fadd_rn(__fadd_rn(__fadd_rn(r[0], r[1]), __fadd_rn(r[2], r[3])),
                     __fadd_rn(__fadd_rn(r[4], r[5]), __fadd_rn(r[6], r[7])));
}

// ---------- main kernel: 128 threads = 2 waves x 32 rows ----------

__global__ __launch_bounds__(128, 2) void k_vq(
    const float* __restrict__ x, const float* __restrict__ dict,
    const float* __restrict__ dictT, const float* __restrict__ dictnorm,
    const unsigned short* __restrict__ packB,
    float* __restrict__ out, double* __restrict__ block_sums)
{
    __shared__ __align__(16) uint4 bstage[2048];   // 32 KB, swizzled [kk][n][(q+(n>>2))&3]
    __shared__ float row_m1[RPB], row_m2[RPB];
    __shared__ int   row_k1[RPB];
    __shared__ float red_d[128];
    __shared__ int   red_k[128];
    __shared__ float wred[2];
    __shared__ int   amb_list[RPB];
    __shared__ int   amb_cnt;

    const int tid  = threadIdx.x;
    const int ln   = tid & 63, wv = tid >> 6;
    const int l15  = ln & 15, q = ln >> 4;
    const int row0 = blockIdx.x * RPB;

    if (tid == 0) amb_cnt = 0;

    // A fragments: 2 row-tiles x 8 kk, register resident (64 VGPRs)
    half8 afrag[2][8];
#pragma unroll
    for (int rt = 0; rt < 2; ++rt) {
        const float* ar = x + (size_t)(row0 + wv * 32 + rt * 16 + l15) * DIM + q * 8;
#pragma unroll
        for (int kk = 0; kk < 8; ++kk) {
            const float4 p0 = *(const float4*)(ar + kk * 32);
            const float4 p1 = *(const float4*)(ar + kk * 32 + 4);
            half8 h;
            h[0] = (_Float16)p0.x; h[1] = (_Float16)p0.y; h[2] = (_Float16)p0.z; h[3] = (_Float16)p0.w;
            h[4] = (_Float16)p1.x; h[5] = (_Float16)p1.y; h[6] = (_Float16)p1.z; h[7] = (_Float16)p1.w;
            afrag[rt][kk] = h;
        }
    }

    // per-lane top-2 for 8 row-slots (2 rt x 4 i); index = wave-uniform c0+t*16
    float m1[8], m2[8]; int j1[8];
#pragma unroll
    for (int s = 0; s < 8; ++s) { m1[s] = 3.0e38f; m2[s] = 3.0e38f; j1[s] = 0x7ffffff0; }

    const uint4* pbu = (const uint4*)packB;
    const int qw = tid & 3, nb = tid >> 2;         // staging coords (nb 0..31)

    // prefetch chunk 0
    uint4 tmp[16];
#pragma unroll
    for (int kk = 0; kk < 8; ++kk)
#pragma unroll
        for (int h = 0; h < 2; ++h)
            tmp[kk * 2 + h] = pbu[kk * 4096 + (nb + h * 32) * 4 + qw];

    for (int cc = 0; cc < 16; ++cc) {
        __syncthreads();                            // prev chunk fully consumed
#pragma unroll
        for (int kk = 0; kk < 8; ++kk)
#pragma unroll
            for (int h = 0; h < 2; ++h) {
                const int n = nb + h * 32;
                bstage[kk * 256 + n * 4 + ((qw + (n >> 2)) & 3)] = tmp[kk * 2 + h];
            }
        __syncthreads();

        if (cc < 15) {                              // prefetch next chunk (overlaps MFMA)
            const int c1 = (cc + 1) * 64;
#pragma unroll
            for (int kk = 0; kk < 8; ++kk)
#pragma unroll
                for (int h = 0; h < 2; ++h)
                    tmp[kk * 2 + h] = pbu[kk * 4096 + (c1 + nb + h * 32) * 4 + qw];
        }

        const int c0 = cc * 64;
        float dn[4];
#pragma unroll
        for (int t = 0; t < 4; ++t) dn[t] = dictnorm[c0 + t * 16 + l15];

        const f32x4 zero = {0.f, 0.f, 0.f, 0.f};
        f32x4 acc[2][4];
#pragma unroll
        for (int t = 0; t < 4; ++t) { acc[0][t] = zero; acc[1][t] = zero; }

#pragma unroll
        for (int kk = 0; kk < 8; ++kk) {
#pragma unroll
            for (int t = 0; t < 4; ++t) {
                const int n = t * 16 + l15;
                const half8 bf = *(const half8*)&bstage[kk * 256 + n * 4 + ((q + (n >> 2)) & 3)];
                acc[0][t] = __builtin_amdgcn_mfma_f32_16x16x32_f16(afrag[0][kk], bf, acc[0][t], 0, 0, 0);
                acc[1][t] = __builtin_amdgcn_mfma_f32_16x16x32_f16(afrag[1][kk], bf, acc[1][t], 0, 0, 0);
            }
        }

#pragma unroll
        for (int t = 0; t < 4; ++t) {
            const int kb = c0 + t * 16;             // wave-uniform (SGPR)
#pragma unroll
            for (int rt = 0; rt < 2; ++rt)
#pragma unroll
                for (int i = 0; i < 4; ++i) {
                    const int sl = rt * 4 + i;
                    const float s = fmaf(-2.f, acc[rt][t][i], dn[t]);
                    const bool c = s < m1[sl];
                    j1[sl] = c ? kb : j1[sl];
                    m2[sl] = __builtin_amdgcn_fmed3f(s, m1[sl], m2[sl]);
                    m1[sl] = fminf(s, m1[sl]);
                }
        }
    }

    // top-2 merge across the 16 lanes sharing quad q
#pragma unroll
    for (int sl = 0; sl < 8; ++sl) {
        float a1 = m1[sl], a2 = m2[sl];
        int   b1 = j1[sl] + l15;                    // full code index
#pragma unroll
        for (int sft = 1; sft < 16; sft <<= 1) {
            const float o1 = __shfl_xor(a1, sft);
            const float o2 = __shfl_xor(a2, sft);
            const int   p1 = __shfl_xor(b1, sft);
            if (o1 < a1 || (o1 == a1 && p1 < b1)) {
                a2 = fminf(a1, o2); a1 = o1; b1 = p1;
            } else {
                a2 = fminf(o1, a2);
            }
        }
        if (l15 == 0) {
            const int rt = sl >> 2, i = sl & 3;
            const int r = wv * 32 + rt * 16 + q * 4 + i;
            row_m1[r] = a1; row_m2[r] = a2; row_k1[r] = b1;
        }
    }
    __syncthreads();

    if (tid < RPB && (row_m2[tid] - row_m1[tid]) < EPS_TIE) {
        int p = atomicAdd(&amb_cnt, 1);
        amb_list[p] = tid;
    }
    __syncthreads();
    const int namb = amb_cnt;

    // np-fp32-faithful full rescan of ambiguous rows (proven in rounds 2/3)
    for (int a = 0; a < namb; ++a) {
        const int r = amb_list[a];
        const float* xr = x + (size_t)(row0 + r) * DIM;
        const float nf = __fadd_rn(np_pairwise_sq_128(xr), np_pairwise_sq_128(xr + 128));
        float bd = 3.4e38f; int bk = 0x7fffffff;
#pragma unroll
        for (int i = 0; i < 8; ++i) {
            const int k = i * 128 + tid;                  // coalesced dict reads
            float sim = 0.f, nd = 0.f;
            for (int d = 0; d < DIM; ++d) {
                const float dv = dict[(size_t)d * NCODE + k];
                const float fv = xr[d];                    // broadcast (L1)
                sim = fmaf(fv, dv, sim);                   // BLAS-style FMA chain, d asc
                nd  = __fadd_rn(nd, __fmul_rn(dv, dv));    // np axis-0 reduce
            }
            const float dist = __fsub_rn(__fadd_rn(nf, nd), __fmul_rn(2.f, sim));
            if (dist < bd) { bd = dist; bk = k; }          // k asc: first-min kept
        }
        red_d[tid] = bd; red_k[tid] = bk;
        __syncthreads();
        for (int s = 64; s > 0; s >>= 1) {
            if (tid < s) {
                const float od = red_d[tid + s]; const int ok = red_k[tid + s];
                if (od < red_d[tid] || (od == red_d[tid] && ok < red_k[tid])) {
                    red_d[tid] = od; red_k[tid] = ok;
                }
            }
            __syncthreads();
        }
        if (tid == 0) row_k1[r] = red_k[0];
        __syncthreads();
    }

    // epilogue: q = 0.5*dictT[kstar]; out = fl(x + fl(q-x)) (np-exact); loss partial
    float lsum = 0.f;
#pragma unroll 4
    for (int it = 0; it < 32; ++it) {
        const int e = it * 512 + tid * 4;
        const int r = e >> 8, d0 = e & 255;
        const int kk = row_k1[r];
        const float4 dv = *(const float4*)&dictT[(size_t)kk * DIM + d0];
        const float4 xv = *(const float4*)&x[(size_t)row0 * DIM + e];
        float4 qv; qv.x = 0.5f * dv.x; qv.y = 0.5f * dv.y; qv.z = 0.5f * dv.z; qv.w = 0.5f * dv.w;
        float4 ov;
        ov.x = __fadd_rn(xv.x, __fsub_rn(qv.x, xv.x));
        ov.y = __fadd_rn(xv.y, __fsub_rn(qv.y, xv.y));
        ov.z = __fadd_rn(xv.z, __fsub_rn(qv.z, xv.z));
        ov.w = __fadd_rn(xv.w, __fsub_rn(qv.w, xv.w));
        const float e0 = __fsub_rn(xv.x, qv.x), e1 = __fsub_rn(xv.y, qv.y);
        const float e2 = __fsub_rn(xv.z, qv.z), e3 = __fsub_rn(xv.w, qv.w);
        lsum += e0 * e0 + e1 * e1 + e2 * e2 + e3 * e3;
        *(float4*)&out[(size_t)row0 * DIM + e] = ov;
    }

#pragma unroll
    for (int sft = 32; sft > 0; sft >>= 1) lsum += __shfl_down(lsum, sft, 64);
    if (ln == 0) wred[wv] = lsum;
    __syncthreads();
    if (tid == 0)
        block_sums[blockIdx.x] = (double)(wred[0] + wred[1]);
}

// ---------- loss finalize (deterministic fp64 reduce of 1024 partials) ----------

__global__ void k_finalize(const double* __restrict__ block_sums, float* __restrict__ out_loss) {
    __shared__ double w[4];
    const int t = threadIdx.x;                  // 256 threads
    double v = block_sums[t] + block_sums[t + 256] + block_sums[t + 512] + block_sums[t + 768];
#pragma unroll
    for (int sft = 32; sft > 0; sft >>= 1) v += __shfl_down(v, sft, 64);
    if ((t & 63) == 0) w[t >> 6] = v;
    __syncthreads();
    if (t == 0) {
        const double tot = (w[0] + w[1]) + (w[2] + w[3]);
        out_loss[0] = (float)(1.25 * tot / (double)(NROWS * DIM));
    }
}

// ---------- launch ----------

extern "C" void kernel_launch(void* const* d_in, const int* in_sizes, int n_in,
                              void* d_out, int out_size, void* d_ws, size_t ws_size,
                              hipStream_t stream) {
    (void)in_sizes; (void)n_in; (void)out_size; (void)ws_size;
    const float* x    = (const float*)d_in[0];
    const float* dict = (const float*)d_in[1];
    float* out = (float*)d_out;

    char* ws = (char*)d_ws;
    float*          dictT      = (float*)ws;                          // 1 MB
    float*          dictnorm   = (float*)(ws + 1048576);              // 4 KB
    double*         block_sums = (double*)(ws + 1048576 + 4096);      // 8 KB
    unsigned short* packB      = (unsigned short*)(ws + 1048576 + 4096 + 8192); // 512 KB

    k_prep<<<292, 256, 0, stream>>>(dict, dictT, dictnorm, packB);
    k_vq<<<NROWS / RPB, 128, 0, stream>>>(x, dict, dictT, dictnorm, packB, out, block_sums);
    k_finalize<<<1, 256, 0, stream>>>(block_sums, out + (size_t)NROWS * DIM);
}

// Round 5
// 397.882 us; speedup vs baseline: 1.1932x; 1.1932x over previous
//
#include <hip/hip_runtime.h>

// VQBlock: x[16,64,64,256] fp32, dict[256,1024] fp32.
// out = concat(q_st flat [16777216], loss [1]) fp32.
//
// Round 5: f16 MFMA fast path with ZERO-VGPR staging:
//  - packB pre-swizzled in k_prep so global contiguous order == LDS swizzled
//    order; staged via __builtin_amdgcn_global_load_lds width=16 (async DMA,
//    wave-uniform LDS base + lane*16).
//  - 256 thr = 4 waves x 32 rows (2 row-tiles per B-frag read), RPB=128.
//  - swizzle slot (q+(n>>2))&3 == (q+(l15>>2))&3 -> one addr VGPR, all
//    ds_read_b128 offsets immediate.
//  - 5-op/candidate top-2 scan (fma, med3, min, cmp+cndmask), SGPR base index.
//  - proven np-faithful fp32 rescan for rows with fast top-2 gap < EPS_TIE.

#define NROWS   65536
#define DIM     256
#define NCODE   1024
#define RPB     128
#define EPS_TIE 4e-3f

typedef _Float16 half8 __attribute__((ext_vector_type(8)));
typedef float    f32x4 __attribute__((ext_vector_type(4)));

// ---------- fused prep kernel ----------
// blocks 0..255: transpose dict -> dictT[k][d]
// blocks 256..259: dictnorm[k] = sum_d dict[d][k]^2
// blocks 260..291: pack dict -> f16 MFMA-B layout, PRE-SWIZZLED:
//   packB_u4[kk*4096 + n*4 + ((q+(n>>2))&3)] = dims (kk*32+q*8 .. +7) of code n
__global__ __launch_bounds__(256) void k_prep(const float* __restrict__ dict,
                                              float* __restrict__ dictT,
                                              float* __restrict__ dictnorm,
                                              unsigned short* __restrict__ packB) {
    const int b = blockIdx.x, tid = threadIdx.x;
    if (b < 256) {
        int t = b * 256 + tid;
#pragma unroll
        for (int i = 0; i < 4; ++i) {
            int e = i * 65536 + t;                    // coalesced read
            int d = e >> 10, k = e & 1023;
            dictT[k * DIM + d] = dict[e];
        }
    } else if (b < 260) {
        int k = (b - 256) * 256 + tid;
        float s = 0.f;
#pragma unroll 8
        for (int d = 0; d < DIM; ++d) {
            float v = dict[d * NCODE + k];
            s = fmaf(v, v, s);
        }
        dictnorm[k] = s;
    } else {
        __shared__ float tile[32][257];
        const int pb = b - 260;                       // 0..31
        const int kk = pb >> 2, kg = pb & 3;
#pragma unroll
        for (int dl = 0; dl < 32; ++dl)
            tile[dl][tid] = dict[(kk * 32 + dl) * NCODE + kg * 256 + tid];  // coalesced
        __syncthreads();
        const int n = kg * 256 + tid;
        uint4* dst = (uint4*)packB + (size_t)kk * 4096 + (size_t)n * 4;
#pragma unroll
        for (int q = 0; q < 4; ++q) {
            unsigned int w[4];
#pragma unroll
            for (int p = 0; p < 4; ++p) {
                _Float16 h0 = (_Float16)tile[q * 8 + p * 2 + 0][tid];
                _Float16 h1 = (_Float16)tile[q * 8 + p * 2 + 1][tid];
                unsigned short u0 = *(unsigned short*)&h0;
                unsigned short u1 = *(unsigned short*)&h1;
                w[p] = (unsigned int)u0 | ((unsigned int)u1 << 16);
            }
            dst[(q + (n >> 2)) & 3] = make_uint4(w[0], w[1], w[2], w[3]);  // swizzled slot
        }
    }
}

// np pairwise sum of squares of 128 contiguous elements
__device__ __forceinline__ float np_pairwise_sq_128(const float* a) {
    float r[8];
#pragma unroll
    for (int j = 0; j < 8; ++j) {
        float v = a[j];
        r[j] = __fmul_rn(v, v);
    }
    for (int i = 8; i < 128; i += 8) {
#pragma unroll
        for (int j = 0; j < 8; ++j) {
            float v = a[i + j];
            r[j] = __fadd_rn(r[j], __fmul_rn(v, v));
        }
    }
    return __fadd_rn(__fadd_rn(__fadd_rn(r[0], r[1]), __fadd_rn(r[2], r[3])),
                     __fadd_rn(__fadd_rn(r[4], r[5]), __fadd_rn(r[6], r[7])));
}

// ---------- main kernel: 256 threads = 4 waves x 32 rows ----------

__global__ __launch_bounds__(256) void k_vq(
    const float* __restrict__ x, const float* __restrict__ dict,
    const float* __restrict__ dictT, const float* __restrict__ dictnorm,
    const unsigned short* __restrict__ packB,
    float* __restrict__ out, double* __restrict__ block_sums)
{
    __shared__ __align__(16) uint4 bstage[2048];   // 32 KB, [kk][n_local][swz slot]
    __shared__ float row_m1[RPB], row_m2[RPB];
    __shared__ int   row_k1[RPB];
    __shared__ float red_d[256];
    __shared__ int   red_k[256];
    __shared__ float wred[4];
    __shared__ int   amb_list[RPB];
    __shared__ int   amb_cnt;

    const int tid  = threadIdx.x;
    const int ln   = tid & 63, wv = tid >> 6;
    const int l15  = ln & 15, q = ln >> 4;
    const int row0 = blockIdx.x * RPB;

    if (tid == 0) amb_cnt = 0;

    // A fragments: 2 row-tiles x 8 kk, register resident (64 VGPRs)
    half8 afrag[2][8];
#pragma unroll
    for (int rt = 0; rt < 2; ++rt) {
        const float* ar = x + (size_t)(row0 + wv * 32 + rt * 16 + l15) * DIM + q * 8;
#pragma unroll
        for (int kk = 0; kk < 8; ++kk) {
            const float4 p0 = *(const float4*)(ar + kk * 32);
            const float4 p1 = *(const float4*)(ar + kk * 32 + 4);
            half8 h;
            h[0] = (_Float16)p0.x; h[1] = (_Float16)p0.y; h[2] = (_Float16)p0.z; h[3] = (_Float16)p0.w;
            h[4] = (_Float16)p1.x; h[5] = (_Float16)p1.y; h[6] = (_Float16)p1.z; h[7] = (_Float16)p1.w;
            afrag[rt][kk] = h;
        }
    }

    // per-lane top-2 for 8 row-slots (2 rt x 4 i); index = wave-uniform kb
    float m1[8], m2[8]; int j1[8];
#pragma unroll
    for (int s = 0; s < 8; ++s) { m1[s] = 3.0e38f; m2[s] = 3.0e38f; j1[s] = 0x7ffffff0; }

    const uint4* pbu = (const uint4*)packB;
    // single lane-dependent LDS read address; all (kk,t) offsets are immediates
    const int swz = (q + (l15 >> 2)) & 3;                 // == (q+(n>>2))&3 for n=t*16+l15
    const uint4* rdbase = &bstage[l15 * 4 + swz];
    uint4* ldst = &bstage[tid & 192];                      // wave segment base (wv*64)

    for (int cc = 0; cc < 16; ++cc) {
        __syncthreads();                                   // prev chunk fully consumed
        {
            const uint4* g0 = pbu + cc * 256 + tid;        // contiguous: global order == LDS order
#pragma unroll
            for (int kk = 0; kk < 8; ++kk)
                __builtin_amdgcn_global_load_lds(
                    (const __attribute__((address_space(1))) unsigned int*)(g0 + kk * 4096),
                    (__attribute__((address_space(3))) unsigned int*)(ldst + kk * 256),
                    16, 0, 0);
        }
        const int c0 = cc * 64;
        float dn[4];
#pragma unroll
        for (int t = 0; t < 4; ++t) dn[t] = dictnorm[c0 + t * 16 + l15];
        __syncthreads();                                   // drains DMA (vmcnt0) + barrier

        const f32x4 zero = {0.f, 0.f, 0.f, 0.f};
        f32x4 acc[2][4];
#pragma unroll
        for (int t = 0; t < 4; ++t) { acc[0][t] = zero; acc[1][t] = zero; }

#pragma unroll
        for (int kk = 0; kk < 8; ++kk) {
#pragma unroll
            for (int t = 0; t < 4; ++t) {
                const half8 bf = *(const half8*)(rdbase + kk * 256 + t * 64);  // imm offsets
                acc[0][t] = __builtin_amdgcn_mfma_f32_16x16x32_f16(afrag[0][kk], bf, acc[0][t], 0, 0, 0);
                acc[1][t] = __builtin_amdgcn_mfma_f32_16x16x32_f16(afrag[1][kk], bf, acc[1][t], 0, 0, 0);
            }
        }

#pragma unroll
        for (int t = 0; t < 4; ++t) {
            const int kb = c0 + t * 16;                    // wave-uniform (SGPR)
#pragma unroll
            for (int rt = 0; rt < 2; ++rt)
#pragma unroll
                for (int i = 0; i < 4; ++i) {
                    const int sl = rt * 4 + i;
                    const float s = fmaf(-2.f, acc[rt][t][i], dn[t]);
                    const bool c = s < m1[sl];
                    j1[sl] = c ? kb : j1[sl];
                    m2[sl] = __builtin_amdgcn_fmed3f(s, m1[sl], m2[sl]);
                    m1[sl] = fminf(s, m1[sl]);
                }
        }
    }

    // top-2 merge across the 16 lanes sharing quad q
#pragma unroll
    for (int sl = 0; sl < 8; ++sl) {
        float a1 = m1[sl], a2 = m2[sl];
        int   b1 = j1[sl] + l15;                           // full code index
#pragma unroll
        for (int sft = 1; sft < 16; sft <<= 1) {
            const float o1 = __shfl_xor(a1, sft);
            const float o2 = __shfl_xor(a2, sft);
            const int   p1 = __shfl_xor(b1, sft);
            if (o1 < a1 || (o1 == a1 && p1 < b1)) {
                a2 = fminf(a1, o2); a1 = o1; b1 = p1;
            } else {
                a2 = fminf(o1, a2);
            }
        }
        if (l15 == 0) {
            const int rt = sl >> 2, i = sl & 3;
            const int r = wv * 32 + rt * 16 + q * 4 + i;
            row_m1[r] = a1; row_m2[r] = a2; row_k1[r] = b1;
        }
    }
    __syncthreads();

    if (tid < RPB && (row_m2[tid] - row_m1[tid]) < EPS_TIE) {
        int p = atomicAdd(&amb_cnt, 1);
        amb_list[p] = tid;
    }
    __syncthreads();
    const int namb = amb_cnt;

    // np-fp32-faithful full rescan of ambiguous rows (proven rounds 2-4)
    for (int a = 0; a < namb; ++a) {
        const int r = amb_list[a];
        const float* xr = x + (size_t)(row0 + r) * DIM;
        const float nf = __fadd_rn(np_pairwise_sq_128(xr), np_pairwise_sq_128(xr + 128));
        float bd = 3.4e38f; int bk = 0x7fffffff;
#pragma unroll
        for (int i = 0; i < 4; ++i) {
            const int k = i * 256 + tid;                   // coalesced dict reads
            float sim = 0.f, nd = 0.f;
            for (int d = 0; d < DIM; ++d) {
                const float dv = dict[(size_t)d * NCODE + k];
                const float fv = xr[d];                    // broadcast (L1)
                sim = fmaf(fv, dv, sim);                   // BLAS-style FMA chain, d asc
                nd  = __fadd_rn(nd, __fmul_rn(dv, dv));    // np axis-0 reduce
            }
            const float dist = __fsub_rn(__fadd_rn(nf, nd), __fmul_rn(2.f, sim));
            if (dist < bd) { bd = dist; bk = k; }          // k asc: first-min kept
        }
        red_d[tid] = bd; red_k[tid] = bk;
        __syncthreads();
        for (int s = 128; s > 0; s >>= 1) {
            if (tid < s) {
                const float od = red_d[tid + s]; const int ok = red_k[tid + s];
                if (od < red_d[tid] || (od == red_d[tid] && ok < red_k[tid])) {
                    red_d[tid] = od; red_k[tid] = ok;
                }
            }
            __syncthreads();
        }
        if (tid == 0) row_k1[r] = red_k[0];
        __syncthreads();
    }

    // epilogue: q = 0.5*dictT[kstar]; out = fl(x + fl(q-x)) (np-exact); loss partial
    float lsum = 0.f;
#pragma unroll 4
    for (int it = 0; it < 32; ++it) {
        const int e = it * 1024 + tid * 4;
        const int r = e >> 8, d0 = e & 255;
        const int kk = row_k1[r];
        const float4 dv = *(const float4*)&dictT[(size_t)kk * DIM + d0];
        const float4 xv = *(const float4*)&x[(size_t)row0 * DIM + e];
        float4 qv; qv.x = 0.5f * dv.x; qv.y = 0.5f * dv.y; qv.z = 0.5f * dv.z; qv.w = 0.5f * dv.w;
        float4 ov;
        ov.x = __fadd_rn(xv.x, __fsub_rn(qv.x, xv.x));
        ov.y = __fadd_rn(xv.y, __fsub_rn(qv.y, xv.y));
        ov.z = __fadd_rn(xv.z, __fsub_rn(qv.z, xv.z));
        ov.w = __fadd_rn(xv.w, __fsub_rn(qv.w, xv.w));
        const float e0 = __fsub_rn(xv.x, qv.x), e1 = __fsub_rn(xv.y, qv.y);
        const float e2 = __fsub_rn(xv.z, qv.z), e3 = __fsub_rn(xv.w, qv.w);
        lsum += e0 * e0 + e1 * e1 + e2 * e2 + e3 * e3;
        *(float4*)&out[(size_t)row0 * DIM + e] = ov;
    }

#pragma unroll
    for (int sft = 32; sft > 0; sft >>= 1) lsum += __shfl_down(lsum, sft, 64);
    if (ln == 0) wred[wv] = lsum;
    __syncthreads();
    if (tid == 0)
        block_sums[blockIdx.x] = (double)((wred[0] + wred[1]) + (wred[2] + wred[3]));
}

// ---------- loss finalize (deterministic fp64 reduce of 512 partials) ----------

__global__ void k_finalize(const double* __restrict__ block_sums, float* __restrict__ out_loss) {
    __shared__ double w[4];
    const int t = threadIdx.x;                  // 256 threads
    double v = block_sums[t] + block_sums[t + 256];
#pragma unroll
    for (int sft = 32; sft > 0; sft >>= 1) v += __shfl_down(v, sft, 64);
    if ((t & 63) == 0) w[t >> 6] = v;
    __syncthreads();
    if (t == 0) {
        const double tot = (w[0] + w[1]) + (w[2] + w[3]);
        out_loss[0] = (float)(1.25 * tot / (double)(NROWS * DIM));
    }
}

// ---------- launch ----------

extern "C" void kernel_launch(void* const* d_in, const int* in_sizes, int n_in,
                              void* d_out, int out_size, void* d_ws, size_t ws_size,
                              hipStream_t stream) {
    (void)in_sizes; (void)n_in; (void)out_size; (void)ws_size;
    const float* x    = (const float*)d_in[0];
    const float* dict = (const float*)d_in[1];
    float* out = (float*)d_out;

    char* ws = (char*)d_ws;
    float*          dictT      = (float*)ws;                          // 1 MB
    float*          dictnorm   = (float*)(ws + 1048576);              // 4 KB
    double*         block_sums = (double*)(ws + 1048576 + 4096);      // 4 KB used
    unsigned short* packB      = (unsigned short*)(ws + 1048576 + 4096 + 8192); // 512 KB

    k_prep<<<292, 256, 0, stream>>>(dict, dictT, dictnorm, packB);
    k_vq<<<NROWS / RPB, 256, 0, stream>>>(x, dict, dictT, dictnorm, packB, out, block_sums);
    k_finalize<<<1, 256, 0, stream>>>(block_sums, out + (size_t)NROWS * DIM);
}